// Round 3
// baseline (604.025 us; speedup 1.0000x reference)
//
#include <hip/hip_runtime.h>

#define E_TOTAL 200000
#define OUTD 5
#define NTILES 1563           // ceil(200000 / 128); last tile has 64 valid edges

typedef __attribute__((ext_vector_type(4))) float f32x4;
typedef __attribute__((ext_vector_type(16))) float f32x16;
typedef __attribute__((ext_vector_type(8))) __bf16 bf16x8;

static __device__ __forceinline__ unsigned short f2bf(float f) {
  union { float f; unsigned u; } v; v.f = f;
  unsigned u = v.u;
  unsigned r = (u + 0x7FFFu + ((u >> 16) & 1u)) >> 16;   // RNE
  return (unsigned short)r;
}

// ---------------------------------------------------------------------------
// Pack W0,W1 [512x512] into 32x32x16-bf16 B-fragment order:
//   lane l holds B[ks*16 + (l>>5)*8 + j][ntile*32 + (l&31)], j=0..7
//   off = ((ntile*32 + ks)*64 + lane)*8 + j
// W2 [512x5] padded N=16 into 16x16x32 B-fragment order.
// ws layout (ushort): [0,262144) W0p | [262144,524288) W1p | [524288,532480) W2p
// byte 1064960: work-steal counter (init 256 here, re-init every launch).
// ---------------------------------------------------------------------------
__global__ __launch_bounds__(256) void pack_weights(
    const float* __restrict__ W0, const float* __restrict__ W1,
    const float* __restrict__ W2, unsigned short* __restrict__ wp) {
  int tid = blockIdx.x * 256 + threadIdx.x;
  if (tid == 0) *(unsigned*)(wp + 532480) = 256u;   // steal counter
  if (tid < 2 * 262144) {
    int sel = tid >> 18;
    int t = tid & 262143;
    int n = t & 511, k = t >> 9;            // coalesced read along n
    const float* W = sel ? W1 : W0;
    float val = W[k * 512 + n];
    int ntile = n >> 5, ks = k >> 4;
    int lane = (((k >> 3) & 1) << 5) | (n & 31);
    int j = k & 7;
    int off = (((ntile * 32 + ks) * 64 + lane) << 3) | j;
    wp[sel * 262144 + off] = f2bf(val);
  } else {
    int t2 = tid - 524288;
    if (t2 < 8192) {                         // W2 padded N=5 -> 16
      int j = t2 & 7, lane = (t2 >> 3) & 63, k0 = t2 >> 9;
      int k = k0 * 32 + ((lane >> 4) << 3) + j;
      int n = lane & 15;
      float val = (n < OUTD) ? W2[k * OUTD + n] : 0.0f;
      wp[524288 + t2] = f2bf(val);
    }
  }
}

// ---------------------------------------------------------------------------
// Persistent fused edge-MLP. Grid = 256 blocks (1/CU), 512 threads (8 waves).
// Tile = 128 edges. LDS: [128][512] bf16 A/H/H2 buffer (131072 B, XOR-swizzled
// byte ^= (row&7)<<4) + 2560 B out-staging + 4 B tnext broadcast.
// Per tile: L0 -> H (in place) -> L1 -> H2 (in place) -> L2 -> obuf -> out.
// Work-stealing: thread 0 atomicAdd's the ws counter during L1 epilogue; all
// threads issue the next tile's 32 gather float4 loads before the L2 phase
// (T14 issue-early / write-late), LDS-write after the post-L2 barrier.
// ---------------------------------------------------------------------------
__global__ __launch_bounds__(512, 2) void edge_mlp(
    const float* __restrict__ x, const int* __restrict__ eidx,
    const float* __restrict__ b0, const float* __restrict__ b1,
    const float* __restrict__ b2, unsigned short* __restrict__ wp,
    float* __restrict__ out) {
  __shared__ uint4 ldsv[8192 + 161];          // 131072 + 2576 B
  unsigned char* lds = (unsigned char*)ldsv;
  float* obuf = (float*)(lds + 131072);       // 128*5 f32
  volatile unsigned* ptn = (unsigned*)(lds + 131072 + 2560);
  unsigned* cnt = (unsigned*)(wp + 532480);

  const int tid = threadIdx.x;
  const int lane = tid & 63;
  const int w = tid >> 6;
  const int l31 = lane & 31, h = lane >> 5;
  const int l15 = lane & 15, q = lane >> 4;
  const int sr = tid >> 2, sp = tid & 3;      // staging row / quarter
  const unsigned ssx = (unsigned)((sr & 7) << 4);
  const unsigned scb = (unsigned)sp * 256;    // staging col byte base

  float4 g[32];

#define STAGE_WRITE(c)                                                         \
  {                                                                            \
    _Pragma("unroll")                                                          \
    for (int k = 0; k < 8; ++k) {                                              \
      const int kk = (k + 2 * sp) & 7;                                         \
      const float4 fa = g[(c) * 16 + 2 * kk];                                  \
      const float4 fb = g[(c) * 16 + 2 * kk + 1];                              \
      uint4 pk;                                                                \
      pk.x = (unsigned)f2bf(fa.x) | ((unsigned)f2bf(fa.y) << 16);              \
      pk.y = (unsigned)f2bf(fa.z) | ((unsigned)f2bf(fa.w) << 16);              \
      pk.z = (unsigned)f2bf(fb.x) | ((unsigned)f2bf(fb.y) << 16);              \
      pk.w = (unsigned)f2bf(fb.z) | ((unsigned)f2bf(fb.w) << 16);              \
      *(uint4*)(lds + (unsigned)sr * 1024 +                                    \
                (((scb + (c) * 128 + (unsigned)kk * 16)) ^ ssx)) = pk;         \
    }                                                                          \
  }

  unsigned t = blockIdx.x;

  // ---- prologue: stage tile t (synchronous)
  {
    int e = (int)t * 128 + sr; if (e >= E_TOTAL) e = E_TOTAL - 1;
    const float* s = x + (size_t)eidx[(sp >> 1) * E_TOTAL + e] * 256 + (sp & 1) * 128;
#pragma unroll
    for (int i = 0; i < 32; ++i) g[i] = *(const float4*)(s + i * 4);
    STAGE_WRITE(0)
    STAGE_WRITE(1)
  }
  __syncthreads();

  for (;;) {
    // ===== layers 0 and 1 =====
#pragma unroll 1
    for (int L = 0; L < 2; ++L) {
      const unsigned short* wl = wp + L * 262144;
      const unsigned short* wbase0 = wl + (size_t)(w * 2) * 16384 + (size_t)lane * 8;
      const unsigned short* wbase1 = wbase0 + 16384;

      f32x16 acc[4][2];
#pragma unroll
      for (int mt = 0; mt < 4; ++mt)
#pragma unroll
        for (int nt = 0; nt < 2; ++nt)
#pragma unroll
          for (int i = 0; i < 16; ++i) acc[mt][nt][i] = 0.f;

      bf16x8 cw0 = *(const bf16x8*)wbase0;
      bf16x8 cw1 = *(const bf16x8*)wbase1;
      bf16x8 nw0 = *(const bf16x8*)(wbase0 + 512);
      bf16x8 nw1 = *(const bf16x8*)(wbase1 + 512);

#pragma unroll 2
      for (int ks = 0; ks < 32; ++ks) {
        const int kp = (ks + 2) & 31;                 // wrapped: branchless
        bf16x8 p0 = *(const bf16x8*)(wbase0 + kp * 512);
        bf16x8 p1 = *(const bf16x8*)(wbase1 + kp * 512);
        const unsigned cb = (unsigned)(ks * 32 + h * 16);
        bf16x8 a[4];
#pragma unroll
        for (int mt = 0; mt < 4; ++mt) {
          const unsigned row = (unsigned)(mt * 32 + l31);
          a[mt] = *(const bf16x8*)(lds + row * 1024 + (cb ^ ((row & 7) << 4)));
        }
#pragma unroll
        for (int mt = 0; mt < 4; ++mt) {
          acc[mt][0] = __builtin_amdgcn_mfma_f32_32x32x16_bf16(a[mt], cw0, acc[mt][0], 0, 0, 0);
          acc[mt][1] = __builtin_amdgcn_mfma_f32_32x32x16_bf16(a[mt], cw1, acc[mt][1], 0, 0, 0);
        }
        cw0 = nw0; cw1 = nw1; nw0 = p0; nw1 = p1;
      }

      // bias + relu + pack to bf16 stash (64 dwords)
      const float* bias = L ? b1 : b0;
      const float bv0 = bias[w * 64 + l31];
      const float bv1 = bias[w * 64 + 32 + l31];
      unsigned sv[4][2][8];
#pragma unroll
      for (int mt = 0; mt < 4; ++mt)
#pragma unroll
        for (int i = 0; i < 8; ++i) {
          float u0 = fmaxf(acc[mt][0][2 * i] + bv0, 0.f);
          float u1 = fmaxf(acc[mt][0][2 * i + 1] + bv0, 0.f);
          sv[mt][0][i] = (unsigned)f2bf(u0) | ((unsigned)f2bf(u1) << 16);
          float v0 = fmaxf(acc[mt][1][2 * i] + bv1, 0.f);
          float v1 = fmaxf(acc[mt][1][2 * i + 1] + bv1, 0.f);
          sv[mt][1][i] = (unsigned)f2bf(v0) | ((unsigned)f2bf(v1) << 16);
        }
      __syncthreads();                 // everyone done reading A/H
      if (L == 1 && tid == 0) *ptn = atomicAdd(cnt, 1u);   // steal next tile
      // write H over A.  C layout: col = lane&31, row = (reg&3)+8*(reg>>2)+4*h
#pragma unroll
      for (int mt = 0; mt < 4; ++mt) {
        const unsigned cb0b = (unsigned)(w * 64 + l31) * 2;
        const unsigned cb1b = (unsigned)(w * 64 + 32 + l31) * 2;
#pragma unroll
        for (int i = 0; i < 8; ++i) {
          const int reg0 = 2 * i, reg1 = 2 * i + 1;
          const unsigned ra = (unsigned)(mt * 32 + (reg0 & 3) + 8 * (reg0 >> 2) + 4 * h);
          const unsigned rb = (unsigned)(mt * 32 + (reg1 & 3) + 8 * (reg1 >> 2) + 4 * h);
          *(unsigned short*)(lds + ra * 1024 + (cb0b ^ ((ra & 7) << 4))) = (unsigned short)(sv[mt][0][i] & 0xffff);
          *(unsigned short*)(lds + rb * 1024 + (cb0b ^ ((rb & 7) << 4))) = (unsigned short)(sv[mt][0][i] >> 16);
          *(unsigned short*)(lds + ra * 1024 + (cb1b ^ ((ra & 7) << 4))) = (unsigned short)(sv[mt][1][i] & 0xffff);
          *(unsigned short*)(lds + rb * 1024 + (cb1b ^ ((rb & 7) << 4))) = (unsigned short)(sv[mt][1][i] >> 16);
        }
      }
      __syncthreads();
    }

    // ===== read stolen tile, issue next gather early (T14) =====
    const unsigned tn = *ptn;
    const int have = (tn < NTILES);
    const float* s2 = x;
    if (have) {
      int e2 = (int)tn * 128 + sr; if (e2 >= E_TOTAL) e2 = E_TOTAL - 1;
      s2 = x + (size_t)eidx[(sp >> 1) * E_TOTAL + e2] * 256 + (sp & 1) * 128;
#pragma unroll
      for (int i = 0; i < 32; ++i) g[i] = *(const float4*)(s2 + i * 4);
    }

    // ===== layer 2: wave w -> rows w*16..w*16+15, N=16 padded =====
    {
      f32x4 acc2; acc2[0] = 0.f; acc2[1] = 0.f; acc2[2] = 0.f; acc2[3] = 0.f;
      const unsigned short* w2b = wp + 524288 + (size_t)lane * 8;
      const unsigned row = (unsigned)(w * 16 + l15);
      const unsigned rsx = (row & 7) << 4;
#pragma unroll
      for (int k0 = 0; k0 < 16; ++k0) {
        bf16x8 a = *(const bf16x8*)(lds + row * 1024 + (((unsigned)(k0 * 64 + q * 16)) ^ rsx));
        bf16x8 b = *(const bf16x8*)(w2b + k0 * 512);
        acc2 = __builtin_amdgcn_mfma_f32_16x16x32_bf16(a, b, acc2, 0, 0, 0);
      }
      if (l15 < OUTD) {
        const float bv = b2[l15];
        const int r0 = w * 16 + q * 4;        // even
        const float m01 = 0.5f * (acc2[0] + acc2[1]) + bv;
        const float m23 = 0.5f * (acc2[2] + acc2[3]) + bv;
        obuf[r0 * OUTD + l15] = m01;
        obuf[(r0 + 1) * OUTD + l15] = m01;
        obuf[(r0 + 2) * OUTD + l15] = m23;
        obuf[(r0 + 3) * OUTD + l15] = m23;
      }
    }
    __syncthreads();                          // H2 reads + obuf writes done

    // ===== coalesced out store =====
    {
      const int ve = (t == NTILES - 1) ? 64 : 128;
      const int nv4 = (ve * OUTD) >> 2;       // 160 or 80 uint4
      uint4* dst = (uint4*)(out + (size_t)t * 640);
      const uint4* sob = (const uint4*)obuf;
      for (int i = tid; i < nv4; i += 512) dst[i] = sob[i];
    }
    if (!have) break;

    // ===== write staged A for next tile =====
    STAGE_WRITE(0)
    STAGE_WRITE(1)
    __syncthreads();
    t = tn;
  }
#undef STAGE_WRITE
}

extern "C" void kernel_launch(void* const* d_in, const int* in_sizes, int n_in,
                              void* d_out, int out_size, void* d_ws, size_t ws_size,
                              hipStream_t stream) {
  const float* x  = (const float*)d_in[0];
  const int* eidx = (const int*)d_in[1];
  const float* W0 = (const float*)d_in[2];
  const float* b0 = (const float*)d_in[3];
  const float* W1 = (const float*)d_in[4];
  const float* b1 = (const float*)d_in[5];
  const float* W2 = (const float*)d_in[6];
  const float* b2 = (const float*)d_in[7];
  float* out = (float*)d_out;
  unsigned short* wp = (unsigned short*)d_ws;
  if (ws_size < 1064964) return;   // 532480 ushorts + 4B counter

  pack_weights<<<2080, 256, 0, stream>>>(W0, W1, W2, wp);
  edge_mlp<<<256, 512, 0, stream>>>(x, eidx, b0, b1, b2, wp, out);
}

// Round 4
// 340.407 us; speedup vs baseline: 1.7744x; 1.7744x over previous
//
#include <hip/hip_runtime.h>

#define E_TOTAL 200000
#define OUTD 5
#define NTILES 1563           // ceil(200000 / 128); last tile has 64 valid edges

typedef __attribute__((ext_vector_type(4))) float f32x4;
typedef __attribute__((ext_vector_type(16))) float f32x16;
typedef __attribute__((ext_vector_type(8))) __bf16 bf16x8;

static __device__ __forceinline__ unsigned short f2bf(float f) {
  union { float f; unsigned u; } v; v.f = f;
  unsigned u = v.u;
  unsigned r = (u + 0x7FFFu + ((u >> 16) & 1u)) >> 16;   // RNE
  return (unsigned short)r;
}

// ---------------------------------------------------------------------------
// Pack W0,W1 [512x512] into 32x32x16-bf16 B-fragment order:
//   lane l holds B[ks*16 + (l>>5)*8 + j][ntile*32 + (l&31)], j=0..7
//   off = ((ntile*32 + ks)*64 + lane)*8 + j
// W2 [512x5] padded N=16 into 16x16x32 B-fragment order.
// ws layout (ushort): [0,262144) W0p | [262144,524288) W1p | [524288,532480) W2p
// ---------------------------------------------------------------------------
__global__ __launch_bounds__(256) void pack_weights(
    const float* __restrict__ W0, const float* __restrict__ W1,
    const float* __restrict__ W2, unsigned short* __restrict__ wp) {
  int tid = blockIdx.x * 256 + threadIdx.x;
  if (tid < 2 * 262144) {
    int sel = tid >> 18;
    int t = tid & 262143;
    int n = t & 511, k = t >> 9;            // coalesced read along n
    const float* W = sel ? W1 : W0;
    float val = W[k * 512 + n];
    int ntile = n >> 5, ks = k >> 4;
    int lane = (((k >> 3) & 1) << 5) | (n & 31);
    int j = k & 7;
    int off = (((ntile * 32 + ks) * 64 + lane) << 3) | j;
    wp[sel * 262144 + off] = f2bf(val);
  } else {
    int t2 = tid - 524288;
    if (t2 < 8192) {                         // W2 padded N=5 -> 16
      int j = t2 & 7, lane = (t2 >> 3) & 63, k0 = t2 >> 9;
      int k = k0 * 32 + ((lane >> 4) << 3) + j;
      int n = lane & 15;
      float val = (n < OUTD) ? W2[k * OUTD + n] : 0.0f;
      wp[524288 + t2] = f2bf(val);
    }
  }
}

// ---------------------------------------------------------------------------
// Fused edge-MLP. One block = 128 edges, 1024 threads (16 waves), 1 block/CU.
// LDS: [128 rows][512 cols] bf16 A/H buffer (131072 B, XOR-swizzled
// byte ^= (row&7)<<4) + 2560 B out-staging.
// Hidden layers: wave w -> rows (w>>3)*64..+63, cols (w&7)*64..+63;
// acc[2][2] of mfma_f32_32x32x16_bf16 (64 VGPRs), 32 k-steps, 2-deep weight
// prefetch (static rotation via unroll 2). H written in place across 2
// barriers. Layer 2: waves 0..7 (16x16x32, N padded to 16), pair-mean
// in-lane, staged to obuf, then full-line uint4 stores.
// VGPR budget: acc 64 + wfrags 24 + a 8 + addr/misc ~18 = ~114 <= 128 cap.
// ---------------------------------------------------------------------------
__global__ __launch_bounds__(1024, 4) void edge_mlp(
    const float* __restrict__ x, const int* __restrict__ eidx,
    const float* __restrict__ b0, const float* __restrict__ b1,
    const float* __restrict__ b2, const unsigned short* __restrict__ wp,
    float* __restrict__ out) {
  __shared__ uint4 ldsv[8192 + 160];          // 131072 + 2560 B
  unsigned char* lds = (unsigned char*)ldsv;
  float* obuf = (float*)(lds + 131072);       // 128*5 f32

  const int tid = threadIdx.x;
  const int lane = tid & 63;
  const int w = tid >> 6;                     // wave 0..15
  const int l31 = lane & 31, h = lane >> 5;
  const int l15 = lane & 15, q = lane >> 4;
  const int mhalf = w >> 3;                   // row half
  const int npair = w & 7;                    // 64-col slice
  const unsigned t = blockIdx.x;

  // ---- stage gathered inputs: A[128][512] bf16, cols 0..255 = x[src], 256..511 = x[dst]
  {
    const int r = tid >> 3, p = tid & 7;      // 8 threads per row
    int e = (int)t * 128 + r; if (e >= E_TOTAL) e = E_TOTAL - 1;
    const float* s = x + (size_t)eidx[(p >> 2) * E_TOTAL + e] * 256 + (p & 3) * 64;
    const unsigned rowb = (unsigned)r * 1024;
    const unsigned sx = (unsigned)((r & 7) << 4);
    const unsigned cb0 = (unsigned)((p >> 2) * 512 + (p & 3) * 128);
#pragma unroll
    for (int jj = 0; jj < 8; ++jj) {
      const int kk = (jj + p) & 7;            // phase by p: conflict-free writes
      const float4 f0 = *(const float4*)(s + kk * 8);
      const float4 f1 = *(const float4*)(s + kk * 8 + 4);
      uint4 pk;
      pk.x = (unsigned)f2bf(f0.x) | ((unsigned)f2bf(f0.y) << 16);
      pk.y = (unsigned)f2bf(f0.z) | ((unsigned)f2bf(f0.w) << 16);
      pk.z = (unsigned)f2bf(f1.x) | ((unsigned)f2bf(f1.y) << 16);
      pk.w = (unsigned)f2bf(f1.z) | ((unsigned)f2bf(f1.w) << 16);
      *(uint4*)(lds + rowb + ((cb0 + (unsigned)kk * 16) ^ sx)) = pk;
    }
  }
  __syncthreads();

  // ===== hidden layers =====
#pragma unroll 1
  for (int L = 0; L < 2; ++L) {
    const unsigned short* wl = wp + L * 262144;
    const unsigned short* wbase0 = wl + (size_t)(npair * 2) * 16384 + (size_t)lane * 8;
    const unsigned short* wbase1 = wbase0 + 16384;

    f32x16 acc00, acc01, acc10, acc11;
#pragma unroll
    for (int i = 0; i < 16; ++i) { acc00[i]=0.f; acc01[i]=0.f; acc10[i]=0.f; acc11[i]=0.f; }

    bf16x8 cw0 = *(const bf16x8*)wbase0;
    bf16x8 cw1 = *(const bf16x8*)wbase1;
    bf16x8 nw0 = *(const bf16x8*)(wbase0 + 512);
    bf16x8 nw1 = *(const bf16x8*)(wbase1 + 512);

#pragma unroll 2
    for (int ks = 0; ks < 32; ++ks) {
      const int kp = (ks + 2) & 31;           // 2-deep prefetch, branchless wrap
      bf16x8 p0 = *(const bf16x8*)(wbase0 + kp * 512);
      bf16x8 p1 = *(const bf16x8*)(wbase1 + kp * 512);
      const unsigned cb = (unsigned)(ks * 32 + h * 16);
      bf16x8 a0, a1;
      {
        const unsigned r0 = (unsigned)(mhalf * 64 + l31);
        const unsigned r1 = r0 + 32;
        a0 = *(const bf16x8*)(lds + r0 * 1024 + (cb ^ ((r0 & 7) << 4)));
        a1 = *(const bf16x8*)(lds + r1 * 1024 + (cb ^ ((r1 & 7) << 4)));
      }
      acc00 = __builtin_amdgcn_mfma_f32_32x32x16_bf16(a0, cw0, acc00, 0, 0, 0);
      acc01 = __builtin_amdgcn_mfma_f32_32x32x16_bf16(a0, cw1, acc01, 0, 0, 0);
      acc10 = __builtin_amdgcn_mfma_f32_32x32x16_bf16(a1, cw0, acc10, 0, 0, 0);
      acc11 = __builtin_amdgcn_mfma_f32_32x32x16_bf16(a1, cw1, acc11, 0, 0, 0);
      cw0 = nw0; cw1 = nw1; nw0 = p0; nw1 = p1;
    }

    // bias + relu + pack to bf16 stash (32 dwords; acc dies as sv fills)
    const float* bias = L ? b1 : b0;
    const float bv0 = bias[npair * 64 + l31];
    const float bv1 = bias[npair * 64 + 32 + l31];
    unsigned sv00[8], sv01[8], sv10[8], sv11[8];
#pragma unroll
    for (int i = 0; i < 8; ++i) {
      float u0 = fmaxf(acc00[2*i] + bv0, 0.f), u1 = fmaxf(acc00[2*i+1] + bv0, 0.f);
      sv00[i] = (unsigned)f2bf(u0) | ((unsigned)f2bf(u1) << 16);
      float v0 = fmaxf(acc01[2*i] + bv1, 0.f), v1 = fmaxf(acc01[2*i+1] + bv1, 0.f);
      sv01[i] = (unsigned)f2bf(v0) | ((unsigned)f2bf(v1) << 16);
      float s0 = fmaxf(acc10[2*i] + bv0, 0.f), s1 = fmaxf(acc10[2*i+1] + bv0, 0.f);
      sv10[i] = (unsigned)f2bf(s0) | ((unsigned)f2bf(s1) << 16);
      float t0 = fmaxf(acc11[2*i] + bv1, 0.f), t1 = fmaxf(acc11[2*i+1] + bv1, 0.f);
      sv11[i] = (unsigned)f2bf(t0) | ((unsigned)f2bf(t1) << 16);
    }
    __syncthreads();                           // all waves done reading A/H

    // write H over A.  C layout: col = lane&31, row = (reg&3)+8*(reg>>2)+4*h
    {
      const unsigned cb0b = (unsigned)(npair * 64 + l31) * 2;
      const unsigned cb1b = cb0b + 64;
#pragma unroll
      for (int i = 0; i < 8; ++i) {
        const int reg0 = 2 * i, reg1 = 2 * i + 1;
        const unsigned base = (unsigned)(mhalf * 64);
        const unsigned ra = base + (unsigned)((reg0 & 3) + 8 * (reg0 >> 2) + 4 * h);
        const unsigned rb = base + (unsigned)((reg1 & 3) + 8 * (reg1 >> 2) + 4 * h);
        const unsigned ra1 = ra + 32, rb1 = rb + 32;
        *(unsigned short*)(lds + ra * 1024 + (cb0b ^ ((ra & 7) << 4))) = (unsigned short)(sv00[i] & 0xffff);
        *(unsigned short*)(lds + rb * 1024 + (cb0b ^ ((rb & 7) << 4))) = (unsigned short)(sv00[i] >> 16);
        *(unsigned short*)(lds + ra * 1024 + (cb1b ^ ((ra & 7) << 4))) = (unsigned short)(sv01[i] & 0xffff);
        *(unsigned short*)(lds + rb * 1024 + (cb1b ^ ((rb & 7) << 4))) = (unsigned short)(sv01[i] >> 16);
        *(unsigned short*)(lds + ra1 * 1024 + (cb0b ^ ((ra1 & 7) << 4))) = (unsigned short)(sv10[i] & 0xffff);
        *(unsigned short*)(lds + rb1 * 1024 + (cb0b ^ ((rb1 & 7) << 4))) = (unsigned short)(sv10[i] >> 16);
        *(unsigned short*)(lds + ra1 * 1024 + (cb1b ^ ((ra1 & 7) << 4))) = (unsigned short)(sv11[i] & 0xffff);
        *(unsigned short*)(lds + rb1 * 1024 + (cb1b ^ ((rb1 & 7) << 4))) = (unsigned short)(sv11[i] >> 16);
      }
    }
    __syncthreads();
  }

  // ===== layer 2: waves 0..7, wave w -> rows w*16..w*16+15, N=16 padded =====
  if (w < 8) {
    f32x4 acc2; acc2[0]=0.f; acc2[1]=0.f; acc2[2]=0.f; acc2[3]=0.f;
    const unsigned short* w2b = wp + 524288 + (size_t)lane * 8;
    const unsigned row = (unsigned)(w * 16 + l15);
    const unsigned rsx = (row & 7) << 4;
#pragma unroll
    for (int k0 = 0; k0 < 16; ++k0) {
      bf16x8 a = *(const bf16x8*)(lds + row * 1024 + (((unsigned)(k0 * 64 + q * 16)) ^ rsx));
      bf16x8 b = *(const bf16x8*)(w2b + k0 * 512);
      acc2 = __builtin_amdgcn_mfma_f32_16x16x32_bf16(a, b, acc2, 0, 0, 0);
    }
    if (l15 < OUTD) {
      const float bv = b2[l15];
      const int r0 = w * 16 + q * 4;          // even
      const float m01 = 0.5f * (acc2[0] + acc2[1]) + bv;
      const float m23 = 0.5f * (acc2[2] + acc2[3]) + bv;
      obuf[r0 * OUTD + l15] = m01;
      obuf[(r0 + 1) * OUTD + l15] = m01;
      obuf[(r0 + 2) * OUTD + l15] = m23;
      obuf[(r0 + 3) * OUTD + l15] = m23;
    }
  }
  __syncthreads();

  // ===== coalesced out store (full 64B lines) =====
  {
    const int ve = (t == NTILES - 1) ? 64 : 128;
    const int nv4 = (ve * OUTD) >> 2;         // 160 or 80 uint4
    uint4* dst = (uint4*)(out + (size_t)t * 640);
    const uint4* sob = (const uint4*)obuf;
    if (tid < nv4) dst[tid] = sob[tid];
  }
}

extern "C" void kernel_launch(void* const* d_in, const int* in_sizes, int n_in,
                              void* d_out, int out_size, void* d_ws, size_t ws_size,
                              hipStream_t stream) {
  const float* x  = (const float*)d_in[0];
  const int* eidx = (const int*)d_in[1];
  const float* W0 = (const float*)d_in[2];
  const float* b0 = (const float*)d_in[3];
  const float* W1 = (const float*)d_in[4];
  const float* b1 = (const float*)d_in[5];
  const float* W2 = (const float*)d_in[6];
  const float* b2 = (const float*)d_in[7];
  float* out = (float*)d_out;
  unsigned short* wp = (unsigned short*)d_ws;
  if (ws_size < 532480u * sizeof(unsigned short)) return;  // ~1.04 MB scratch

  pack_weights<<<2080, 256, 0, stream>>>(W0, W1, W2, wp);
  edge_mlp<<<NTILES, 1024, 0, stream>>>(x, eidx, b0, b1, b2, wp, out);
}

// Round 5
// 278.056 us; speedup vs baseline: 2.1723x; 1.2242x over previous
//
#include <hip/hip_runtime.h>

#define E_TOTAL 200000
#define OUTD 5
#define NTILES 1563           // ceil(200000 / 128); last tile has 64 valid edges
#define WP_USHORTS 532480     // W0p (262144) + W1p (262144) + W2p (8192)
#define XBF_USHORTS 2560000   // 10000 * 256 bf16 copy of x

typedef __attribute__((ext_vector_type(4))) float f32x4;
typedef __attribute__((ext_vector_type(16))) float f32x16;
typedef __attribute__((ext_vector_type(8))) __bf16 bf16x8;

static __device__ __forceinline__ unsigned short f2bf(float f) {
  union { float f; unsigned u; } v; v.f = f;
  unsigned u = v.u;
  unsigned r = (u + 0x7FFFu + ((u >> 16) & 1u)) >> 16;   // RNE
  return (unsigned short)r;
}
static __device__ __forceinline__ unsigned short f2bf_cast(float f) {
  __bf16 h = (__bf16)f;                                   // HW cvt, RNE
  return __builtin_bit_cast(unsigned short, h);
}

// ---------------------------------------------------------------------------
// Pack W0,W1 [512x512] into 32x32x16-bf16 B-fragment order:
//   lane l holds B[ks*16 + (l>>5)*8 + j][ntile*32 + (l&31)], j=0..7
//   off = ((ntile*32 + ks)*64 + lane)*8 + j
// W2 [512x5] padded N=16 into 16x16x32 B-fragment order.
// ws layout (ushort): [0,262144) W0p | [262144,524288) W1p | [524288,532480) W2p
//                     [532480, 532480+2560000) xbf (if ws_size permits)
// ---------------------------------------------------------------------------
__global__ __launch_bounds__(256) void pack_weights(
    const float* __restrict__ W0, const float* __restrict__ W1,
    const float* __restrict__ W2, unsigned short* __restrict__ wp) {
  int tid = blockIdx.x * 256 + threadIdx.x;
  if (tid < 2 * 262144) {
    int sel = tid >> 18;
    int t = tid & 262143;
    int n = t & 511, k = t >> 9;            // coalesced read along n
    const float* W = sel ? W1 : W0;
    float val = W[k * 512 + n];
    int ntile = n >> 5, ks = k >> 4;
    int lane = (((k >> 3) & 1) << 5) | (n & 31);
    int j = k & 7;
    int off = (((ntile * 32 + ks) * 64 + lane) << 3) | j;
    wp[sel * 262144 + off] = f2bf(val);
  } else {
    int t2 = tid - 524288;
    if (t2 < 8192) {                         // W2 padded N=5 -> 16
      int j = t2 & 7, lane = (t2 >> 3) & 63, k0 = t2 >> 9;
      int k = k0 * 32 + ((lane >> 4) << 3) + j;
      int n = lane & 15;
      float val = (n < OUTD) ? W2[k * OUTD + n] : 0.0f;
      wp[524288 + t2] = f2bf(val);
    }
  }
}

// fp32 x -> bf16 copy (one-shot, memory-bound, ~3 µs)
__global__ __launch_bounds__(256) void convert_x(
    const float* __restrict__ x, unsigned short* __restrict__ xbf) {
  int i = blockIdx.x * 256 + threadIdx.x;    // 8 elems each
  if (i < 320000) {
    const float4 f0 = *(const float4*)(x + (size_t)i * 8);
    const float4 f1 = *(const float4*)(x + (size_t)i * 8 + 4);
    uint4 pk;
    pk.x = (unsigned)f2bf(f0.x) | ((unsigned)f2bf(f0.y) << 16);
    pk.y = (unsigned)f2bf(f0.z) | ((unsigned)f2bf(f0.w) << 16);
    pk.z = (unsigned)f2bf(f1.x) | ((unsigned)f2bf(f1.y) << 16);
    pk.w = (unsigned)f2bf(f1.z) | ((unsigned)f2bf(f1.w) << 16);
    *(uint4*)(xbf + (size_t)i * 8) = pk;
  }
}

// ---------------------------------------------------------------------------
// Fused edge-MLP. One block = 128 edges, 1024 threads (16 waves), 1 block/CU.
// LDS: [128 rows][512 cols] bf16 A/H buffer (131072 B, XOR-swizzled
// byte ^= (row&7)<<4) + 2560 B out-staging.
// Hidden layers: wave w -> rows (w>>3)*64..+63, cols (w&7)*64..+63;
// acc[2][2] of mfma_f32_32x32x16_bf16 (64 AGPRs), bias preloaded into C-in,
// 32 k-steps, 2-deep weight prefetch. Barrier comes BEFORE the epilogue so
// only AGPRs (not an sv[] stash) live across it -> no scratch spill.
// XBF=1: stage from pre-converted bf16 x (no VALU cvt in staging).
// ---------------------------------------------------------------------------
template <int XBF>
__global__ __launch_bounds__(1024, 4) void edge_mlp(
    const float* __restrict__ x, const unsigned short* __restrict__ xbf,
    const int* __restrict__ eidx,
    const float* __restrict__ b0, const float* __restrict__ b1,
    const float* __restrict__ b2, const unsigned short* __restrict__ wp,
    float* __restrict__ out) {
  __shared__ uint4 ldsv[8192 + 160];          // 131072 + 2560 B
  unsigned char* lds = (unsigned char*)ldsv;
  float* obuf = (float*)(lds + 131072);       // 128*5 f32

  const int tid = threadIdx.x;
  const int lane = tid & 63;
  const int w = tid >> 6;                     // wave 0..15
  const int l31 = lane & 31, h = lane >> 5;
  const int l15 = lane & 15, q = lane >> 4;
  const int mhalf = w >> 3;                   // row half
  const int npair = w & 7;                    // 64-col slice
  const unsigned t = blockIdx.x;

  // ---- stage gathered inputs: A[128][512] bf16, cols 0..255 = x[src], 256..511 = x[dst]
  {
    const int r = tid >> 3, p = tid & 7;      // 8 threads per row
    int e = (int)t * 128 + r; if (e >= E_TOTAL) e = E_TOTAL - 1;
    const int node = eidx[(p >> 2) * E_TOTAL + e];
    const unsigned rowb = (unsigned)r * 1024;
    const unsigned sx = (unsigned)((r & 7) << 4);
    const unsigned cb0 = (unsigned)((p >> 2) * 512 + (p & 3) * 128);
    if (XBF) {
      const unsigned short* s = xbf + (size_t)node * 256 + (p & 3) * 64;
#pragma unroll
      for (int jj = 0; jj < 8; ++jj) {
        const int kk = (jj + p) & 7;          // phase by p: conflict-free writes
        uint4 pk = *(const uint4*)(s + kk * 8);
        *(uint4*)(lds + rowb + ((cb0 + (unsigned)kk * 16) ^ sx)) = pk;
      }
    } else {
      const float* s = x + (size_t)node * 256 + (p & 3) * 64;
#pragma unroll
      for (int jj = 0; jj < 8; ++jj) {
        const int kk = (jj + p) & 7;
        const float4 f0 = *(const float4*)(s + kk * 8);
        const float4 f1 = *(const float4*)(s + kk * 8 + 4);
        uint4 pk;
        pk.x = (unsigned)f2bf(f0.x) | ((unsigned)f2bf(f0.y) << 16);
        pk.y = (unsigned)f2bf(f0.z) | ((unsigned)f2bf(f0.w) << 16);
        pk.z = (unsigned)f2bf(f1.x) | ((unsigned)f2bf(f1.y) << 16);
        pk.w = (unsigned)f2bf(f1.z) | ((unsigned)f2bf(f1.w) << 16);
        *(uint4*)(lds + rowb + ((cb0 + (unsigned)kk * 16) ^ sx)) = pk;
      }
    }
  }
  __syncthreads();

  // ===== hidden layers =====
#pragma unroll 1
  for (int L = 0; L < 2; ++L) {
    const unsigned short* wl = wp + L * 262144;
    const unsigned short* wbase0 = wl + (size_t)(npair * 2) * 16384 + (size_t)lane * 8;
    const unsigned short* wbase1 = wbase0 + 16384;
    const float* bias = L ? b1 : b0;
    const float bv0 = bias[npair * 64 + l31];
    const float bv1 = bias[npair * 64 + 32 + l31];

    // bias preloaded as C-in (C layout: col = lane&31 -> same bias all regs)
    f32x16 acc00, acc01, acc10, acc11;
#pragma unroll
    for (int i = 0; i < 16; ++i) { acc00[i]=bv0; acc01[i]=bv1; acc10[i]=bv0; acc11[i]=bv1; }

    bf16x8 cw0 = *(const bf16x8*)wbase0;
    bf16x8 cw1 = *(const bf16x8*)wbase1;
    bf16x8 nw0 = *(const bf16x8*)(wbase0 + 512);
    bf16x8 nw1 = *(const bf16x8*)(wbase1 + 512);

#pragma unroll 2
    for (int ks = 0; ks < 32; ++ks) {
      const int kp = (ks + 2) & 31;           // 2-deep prefetch, branchless wrap
      bf16x8 p0 = *(const bf16x8*)(wbase0 + kp * 512);
      bf16x8 p1 = *(const bf16x8*)(wbase1 + kp * 512);
      const unsigned cb = (unsigned)(ks * 32 + h * 16);
      bf16x8 a0, a1;
      {
        const unsigned r0 = (unsigned)(mhalf * 64 + l31);
        const unsigned r1 = r0 + 32;
        a0 = *(const bf16x8*)(lds + r0 * 1024 + (cb ^ ((r0 & 7) << 4)));
        a1 = *(const bf16x8*)(lds + r1 * 1024 + (cb ^ ((r1 & 7) << 4)));
      }
      acc00 = __builtin_amdgcn_mfma_f32_32x32x16_bf16(a0, cw0, acc00, 0, 0, 0);
      acc01 = __builtin_amdgcn_mfma_f32_32x32x16_bf16(a0, cw1, acc01, 0, 0, 0);
      acc10 = __builtin_amdgcn_mfma_f32_32x32x16_bf16(a1, cw0, acc10, 0, 0, 0);
      acc11 = __builtin_amdgcn_mfma_f32_32x32x16_bf16(a1, cw1, acc11, 0, 0, 0);
      cw0 = nw0; cw1 = nw1; nw0 = p0; nw1 = p1;
    }

    __syncthreads();   // all waves done reading A/H; only AGPR acc lives across

    // relu + cvt + write H over A.  C layout: col = lane&31,
    // row = (reg&3) + 8*(reg>>2) + 4*h
    {
      const unsigned cb0b = (unsigned)(npair * 64 + l31) * 2;
      const unsigned cb1b = cb0b + 64;
      const unsigned base = (unsigned)(mhalf * 64);
#pragma unroll
      for (int i = 0; i < 8; ++i) {
        const int reg0 = 2 * i, reg1 = 2 * i + 1;
        const unsigned ra = base + (unsigned)((reg0 & 3) + 8 * (reg0 >> 2) + 4 * h);
        const unsigned rb = base + (unsigned)((reg1 & 3) + 8 * (reg1 >> 2) + 4 * h);
        const unsigned ra1 = ra + 32, rb1 = rb + 32;
        *(unsigned short*)(lds + ra * 1024 + (cb0b ^ ((ra & 7) << 4))) = f2bf_cast(fmaxf(acc00[2*i], 0.f));
        *(unsigned short*)(lds + rb * 1024 + (cb0b ^ ((rb & 7) << 4))) = f2bf_cast(fmaxf(acc00[2*i+1], 0.f));
        *(unsigned short*)(lds + ra * 1024 + (cb1b ^ ((ra & 7) << 4))) = f2bf_cast(fmaxf(acc01[2*i], 0.f));
        *(unsigned short*)(lds + rb * 1024 + (cb1b ^ ((rb & 7) << 4))) = f2bf_cast(fmaxf(acc01[2*i+1], 0.f));
        *(unsigned short*)(lds + ra1 * 1024 + (cb0b ^ ((ra1 & 7) << 4))) = f2bf_cast(fmaxf(acc10[2*i], 0.f));
        *(unsigned short*)(lds + rb1 * 1024 + (cb0b ^ ((rb1 & 7) << 4))) = f2bf_cast(fmaxf(acc10[2*i+1], 0.f));
        *(unsigned short*)(lds + ra1 * 1024 + (cb1b ^ ((ra1 & 7) << 4))) = f2bf_cast(fmaxf(acc11[2*i], 0.f));
        *(unsigned short*)(lds + rb1 * 1024 + (cb1b ^ ((rb1 & 7) << 4))) = f2bf_cast(fmaxf(acc11[2*i+1], 0.f));
      }
    }
    __syncthreads();
  }

  // ===== layer 2: waves 0..7, wave w -> rows w*16..w*16+15, N=16 padded =====
  if (w < 8) {
    f32x4 acc2; acc2[0]=0.f; acc2[1]=0.f; acc2[2]=0.f; acc2[3]=0.f;
    const unsigned short* w2b = wp + 524288 + (size_t)lane * 8;
    const unsigned row = (unsigned)(w * 16 + l15);
    const unsigned rsx = (row & 7) << 4;
#pragma unroll
    for (int k0 = 0; k0 < 16; ++k0) {
      bf16x8 a = *(const bf16x8*)(lds + row * 1024 + (((unsigned)(k0 * 64 + q * 16)) ^ rsx));
      bf16x8 b = *(const bf16x8*)(w2b + k0 * 512);
      acc2 = __builtin_amdgcn_mfma_f32_16x16x32_bf16(a, b, acc2, 0, 0, 0);
    }
    if (l15 < OUTD) {
      const float bv = b2[l15];
      const int r0 = w * 16 + q * 4;          // even
      const float m01 = 0.5f * (acc2[0] + acc2[1]) + bv;
      const float m23 = 0.5f * (acc2[2] + acc2[3]) + bv;
      obuf[r0 * OUTD + l15] = m01;
      obuf[(r0 + 1) * OUTD + l15] = m01;
      obuf[(r0 + 2) * OUTD + l15] = m23;
      obuf[(r0 + 3) * OUTD + l15] = m23;
    }
  }
  __syncthreads();

  // ===== coalesced out store (full 64B lines) =====
  {
    const int ve = (t == NTILES - 1) ? 64 : 128;
    const int nv4 = (ve * OUTD) >> 2;         // 160 or 80 uint4
    uint4* dst = (uint4*)(out + (size_t)t * 640);
    const uint4* sob = (const uint4*)obuf;
    if (tid < nv4) dst[tid] = sob[tid];
  }
}

extern "C" void kernel_launch(void* const* d_in, const int* in_sizes, int n_in,
                              void* d_out, int out_size, void* d_ws, size_t ws_size,
                              hipStream_t stream) {
  const float* x  = (const float*)d_in[0];
  const int* eidx = (const int*)d_in[1];
  const float* W0 = (const float*)d_in[2];
  const float* b0 = (const float*)d_in[3];
  const float* W1 = (const float*)d_in[4];
  const float* b1 = (const float*)d_in[5];
  const float* W2 = (const float*)d_in[6];
  const float* b2 = (const float*)d_in[7];
  float* out = (float*)d_out;
  unsigned short* wp = (unsigned short*)d_ws;
  if (ws_size < (size_t)WP_USHORTS * 2) return;   // ~1.04 MB minimum

  pack_weights<<<2080, 256, 0, stream>>>(W0, W1, W2, wp);
  if (ws_size >= (size_t)(WP_USHORTS + XBF_USHORTS) * 2) {
    unsigned short* xbf = wp + WP_USHORTS;
    convert_x<<<1250, 256, 0, stream>>>(x, xbf);
    edge_mlp<1><<<NTILES, 1024, 0, stream>>>(x, xbf, eidx, b0, b1, b2, wp, out);
  } else {
    edge_mlp<0><<<NTILES, 1024, 0, stream>>>(x, nullptr, eidx, b0, b1, b2, wp, out);
  }
}

// Round 6
// 243.551 us; speedup vs baseline: 2.4801x; 1.1417x over previous
//
#include <hip/hip_runtime.h>

#define E_TOTAL 200000
#define OUTD 5
#define NTILES 3125           // 200000 / 64 exactly, no tail
#define WP_USHORTS 532480     // W0p (262144) + W1p (262144) + W2p (8192)
#define XBF_USHORTS 2560000   // 10000 * 256 bf16 copy of x

typedef __attribute__((ext_vector_type(4))) float f32x4;
typedef __attribute__((ext_vector_type(16))) float f32x16;
typedef __attribute__((ext_vector_type(8))) __bf16 bf16x8;

static __device__ __forceinline__ unsigned short f2bf(float f) {
  union { float f; unsigned u; } v; v.f = f;
  unsigned u = v.u;
  unsigned r = (u + 0x7FFFu + ((u >> 16) & 1u)) >> 16;   // RNE
  return (unsigned short)r;
}
static __device__ __forceinline__ unsigned short f2bf_cast(float f) {
  __bf16 h = (__bf16)f;                                   // HW cvt, RNE
  return __builtin_bit_cast(unsigned short, h);
}

// ---------------------------------------------------------------------------
// Pack W0,W1 [512x512] into 32x32x16-bf16 B-fragment order:
//   lane l holds B[ks*16 + (l>>5)*8 + j][ntile*32 + (l&31)], j=0..7
//   off = ((ntile*32 + ks)*64 + lane)*8 + j
// W2 [512x5] padded N=16 into 16x16x32 B-fragment order.
// ws layout (ushort): [0,262144) W0p | [262144,524288) W1p | [524288,532480) W2p
//                     [532480, 532480+2560000) xbf (if ws_size permits)
// ---------------------------------------------------------------------------
__global__ __launch_bounds__(256) void pack_weights(
    const float* __restrict__ W0, const float* __restrict__ W1,
    const float* __restrict__ W2, unsigned short* __restrict__ wp) {
  int tid = blockIdx.x * 256 + threadIdx.x;
  if (tid < 2 * 262144) {
    int sel = tid >> 18;
    int t = tid & 262143;
    int n = t & 511, k = t >> 9;            // coalesced read along n
    const float* W = sel ? W1 : W0;
    float val = W[k * 512 + n];
    int ntile = n >> 5, ks = k >> 4;
    int lane = (((k >> 3) & 1) << 5) | (n & 31);
    int j = k & 7;
    int off = (((ntile * 32 + ks) * 64 + lane) << 3) | j;
    wp[sel * 262144 + off] = f2bf(val);
  } else {
    int t2 = tid - 524288;
    if (t2 < 8192) {                         // W2 padded N=5 -> 16
      int j = t2 & 7, lane = (t2 >> 3) & 63, k0 = t2 >> 9;
      int k = k0 * 32 + ((lane >> 4) << 3) + j;
      int n = lane & 15;
      float val = (n < OUTD) ? W2[k * OUTD + n] : 0.0f;
      wp[524288 + t2] = f2bf(val);
    }
  }
}

// fp32 x -> bf16 copy (one-shot, memory-bound)
__global__ __launch_bounds__(256) void convert_x(
    const float* __restrict__ x, unsigned short* __restrict__ xbf) {
  int i = blockIdx.x * 256 + threadIdx.x;    // 8 elems each
  if (i < 320000) {
    const float4 f0 = *(const float4*)(x + (size_t)i * 8);
    const float4 f1 = *(const float4*)(x + (size_t)i * 8 + 4);
    uint4 pk;
    pk.x = (unsigned)f2bf(f0.x) | ((unsigned)f2bf(f0.y) << 16);
    pk.y = (unsigned)f2bf(f0.z) | ((unsigned)f2bf(f0.w) << 16);
    pk.z = (unsigned)f2bf(f1.x) | ((unsigned)f2bf(f1.y) << 16);
    pk.w = (unsigned)f2bf(f1.z) | ((unsigned)f2bf(f1.w) << 16);
    *(uint4*)(xbf + (size_t)i * 8) = pk;
  }
}

// ---------------------------------------------------------------------------
// Fused edge-MLP. One block = 64 edges, 512 threads (8 waves).
// LDS: [64 rows][512 cols] bf16 A/H buffer (65536 B, XOR-swizzled
// byte ^= (row&7)<<4) + 1280 B out-staging = 66816 B -> 2 blocks/CU.
// Two independent blocks per CU: one block's staging/epilogue/store phases
// overlap the other's MFMA k-loop (no shared barriers).
// Hidden layers: wave w -> all 64 rows, cols w*64..w*64+63; acc[2][2] of
// mfma_f32_32x32x16_bf16 (64 AGPRs), bias preloaded into C-in, 32 k-steps,
// 2-deep weight prefetch, s_setprio(1) around the MFMA cluster (T5).
// Barrier BEFORE the epilogue so only AGPRs live across it -> no spill.
// ---------------------------------------------------------------------------
template <int XBF>
__global__ __launch_bounds__(512, 4) void edge_mlp(
    const float* __restrict__ x, const unsigned short* __restrict__ xbf,
    const int* __restrict__ eidx,
    const float* __restrict__ b0, const float* __restrict__ b1,
    const float* __restrict__ b2, const unsigned short* __restrict__ wp,
    float* __restrict__ out) {
  __shared__ uint4 ldsv[4096 + 80];           // 65536 + 1280 B
  unsigned char* lds = (unsigned char*)ldsv;
  float* obuf = (float*)(lds + 65536);        // 64*5 f32

  const int tid = threadIdx.x;
  const int lane = tid & 63;
  const int w = tid >> 6;                     // wave 0..7
  const int l31 = lane & 31, h = lane >> 5;
  const int l15 = lane & 15, q = lane >> 4;
  const unsigned t = blockIdx.x;

  // ---- stage gathered inputs: A[64][512] bf16, cols 0..255 = x[src], 256..511 = x[dst]
  {
    const int r = tid >> 3, p = tid & 7;      // 8 threads per row
    const int e = (int)t * 64 + r;            // grid exact: e < E_TOTAL always
    const int node = eidx[(p >> 2) * E_TOTAL + e];
    const unsigned rowb = (unsigned)r * 1024;
    const unsigned sx = (unsigned)((r & 7) << 4);
    const unsigned cb0 = (unsigned)((p >> 2) * 512 + (p & 3) * 128);
    if (XBF) {
      const unsigned short* s = xbf + (size_t)node * 256 + (p & 3) * 64;
#pragma unroll
      for (int jj = 0; jj < 8; ++jj) {
        const int kk = (jj + p) & 7;          // phase by p: conflict-free writes
        uint4 pk = *(const uint4*)(s + kk * 8);
        *(uint4*)(lds + rowb + ((cb0 + (unsigned)kk * 16) ^ sx)) = pk;
      }
    } else {
      const float* s = x + (size_t)node * 256 + (p & 3) * 64;
#pragma unroll
      for (int jj = 0; jj < 8; ++jj) {
        const int kk = (jj + p) & 7;
        const float4 f0 = *(const float4*)(s + kk * 8);
        const float4 f1 = *(const float4*)(s + kk * 8 + 4);
        uint4 pk;
        pk.x = (unsigned)f2bf(f0.x) | ((unsigned)f2bf(f0.y) << 16);
        pk.y = (unsigned)f2bf(f0.z) | ((unsigned)f2bf(f0.w) << 16);
        pk.z = (unsigned)f2bf(f1.x) | ((unsigned)f2bf(f1.y) << 16);
        pk.w = (unsigned)f2bf(f1.z) | ((unsigned)f2bf(f1.w) << 16);
        *(uint4*)(lds + rowb + ((cb0 + (unsigned)kk * 16) ^ sx)) = pk;
      }
    }
  }
  __syncthreads();

  // ===== hidden layers =====
#pragma unroll 1
  for (int L = 0; L < 2; ++L) {
    const unsigned short* wl = wp + L * 262144;
    const unsigned short* wbase0 = wl + (size_t)(w * 2) * 16384 + (size_t)lane * 8;
    const unsigned short* wbase1 = wbase0 + 16384;
    const float* bias = L ? b1 : b0;
    const float bv0 = bias[w * 64 + l31];
    const float bv1 = bias[w * 64 + 32 + l31];

    // bias preloaded as C-in (C layout: col = lane&31 -> same bias all regs)
    f32x16 acc00, acc01, acc10, acc11;
#pragma unroll
    for (int i = 0; i < 16; ++i) { acc00[i]=bv0; acc01[i]=bv1; acc10[i]=bv0; acc11[i]=bv1; }

    bf16x8 cw0 = *(const bf16x8*)wbase0;
    bf16x8 cw1 = *(const bf16x8*)wbase1;
    bf16x8 nw0 = *(const bf16x8*)(wbase0 + 512);
    bf16x8 nw1 = *(const bf16x8*)(wbase1 + 512);

#pragma unroll 4
    for (int ks = 0; ks < 32; ++ks) {
      const int kp = (ks + 2) & 31;           // 2-deep prefetch, branchless wrap
      bf16x8 p0 = *(const bf16x8*)(wbase0 + kp * 512);
      bf16x8 p1 = *(const bf16x8*)(wbase1 + kp * 512);
      const unsigned cb = (unsigned)(ks * 32 + h * 16);
      bf16x8 a0, a1;
      {
        const unsigned r0 = (unsigned)l31;
        const unsigned r1 = r0 + 32;
        a0 = *(const bf16x8*)(lds + r0 * 1024 + (cb ^ ((r0 & 7) << 4)));
        a1 = *(const bf16x8*)(lds + r1 * 1024 + (cb ^ ((r1 & 7) << 4)));
      }
      __builtin_amdgcn_s_setprio(1);
      acc00 = __builtin_amdgcn_mfma_f32_32x32x16_bf16(a0, cw0, acc00, 0, 0, 0);
      acc01 = __builtin_amdgcn_mfma_f32_32x32x16_bf16(a0, cw1, acc01, 0, 0, 0);
      acc10 = __builtin_amdgcn_mfma_f32_32x32x16_bf16(a1, cw0, acc10, 0, 0, 0);
      acc11 = __builtin_amdgcn_mfma_f32_32x32x16_bf16(a1, cw1, acc11, 0, 0, 0);
      __builtin_amdgcn_s_setprio(0);
      cw0 = nw0; cw1 = nw1; nw0 = p0; nw1 = p1;
    }

    __syncthreads();   // all waves done reading A/H; only AGPR acc lives across

    // relu + cvt + write H over A.  C layout: col = lane&31,
    // row = (reg&3) + 8*(reg>>2) + 4*h
    {
      const unsigned cb0b = (unsigned)(w * 64 + l31) * 2;
      const unsigned cb1b = cb0b + 64;
#pragma unroll
      for (int i = 0; i < 8; ++i) {
        const int reg0 = 2 * i, reg1 = 2 * i + 1;
        const unsigned ra = (unsigned)((reg0 & 3) + 8 * (reg0 >> 2) + 4 * h);
        const unsigned rb = (unsigned)((reg1 & 3) + 8 * (reg1 >> 2) + 4 * h);
        const unsigned ra1 = ra + 32, rb1 = rb + 32;
        *(unsigned short*)(lds + ra * 1024 + (cb0b ^ ((ra & 7) << 4))) = f2bf_cast(fmaxf(acc00[2*i], 0.f));
        *(unsigned short*)(lds + rb * 1024 + (cb0b ^ ((rb & 7) << 4))) = f2bf_cast(fmaxf(acc00[2*i+1], 0.f));
        *(unsigned short*)(lds + ra * 1024 + (cb1b ^ ((ra & 7) << 4))) = f2bf_cast(fmaxf(acc01[2*i], 0.f));
        *(unsigned short*)(lds + rb * 1024 + (cb1b ^ ((rb & 7) << 4))) = f2bf_cast(fmaxf(acc01[2*i+1], 0.f));
        *(unsigned short*)(lds + ra1 * 1024 + (cb0b ^ ((ra1 & 7) << 4))) = f2bf_cast(fmaxf(acc10[2*i], 0.f));
        *(unsigned short*)(lds + rb1 * 1024 + (cb0b ^ ((rb1 & 7) << 4))) = f2bf_cast(fmaxf(acc10[2*i+1], 0.f));
        *(unsigned short*)(lds + ra1 * 1024 + (cb1b ^ ((ra1 & 7) << 4))) = f2bf_cast(fmaxf(acc11[2*i], 0.f));
        *(unsigned short*)(lds + rb1 * 1024 + (cb1b ^ ((rb1 & 7) << 4))) = f2bf_cast(fmaxf(acc11[2*i+1], 0.f));
      }
    }
    __syncthreads();
  }

  // ===== layer 2: waves 0..3, wave w -> rows w*16..w*16+15, N=16 padded =====
  if (w < 4) {
    f32x4 acc2; acc2[0]=0.f; acc2[1]=0.f; acc2[2]=0.f; acc2[3]=0.f;
    const unsigned short* w2b = wp + 524288 + (size_t)lane * 8;
    const unsigned row = (unsigned)(w * 16 + l15);
    const unsigned rsx = (row & 7) << 4;
#pragma unroll
    for (int k0 = 0; k0 < 16; ++k0) {
      bf16x8 a = *(const bf16x8*)(lds + row * 1024 + (((unsigned)(k0 * 64 + q * 16)) ^ rsx));
      bf16x8 b = *(const bf16x8*)(w2b + k0 * 512);
      acc2 = __builtin_amdgcn_mfma_f32_16x16x32_bf16(a, b, acc2, 0, 0, 0);
    }
    if (l15 < OUTD) {
      const float bv = b2[l15];
      const int r0 = w * 16 + q * 4;          // even
      const float m01 = 0.5f * (acc2[0] + acc2[1]) + bv;
      const float m23 = 0.5f * (acc2[2] + acc2[3]) + bv;
      obuf[r0 * OUTD + l15] = m01;
      obuf[(r0 + 1) * OUTD + l15] = m01;
      obuf[(r0 + 2) * OUTD + l15] = m23;
      obuf[(r0 + 3) * OUTD + l15] = m23;
    }
  }
  __syncthreads();

  // ===== coalesced out store (full 64B lines; 64*5*4B = 20 lines) =====
  {
    uint4* dst = (uint4*)(out + (size_t)t * 320);
    const uint4* sob = (const uint4*)obuf;
    if (tid < 80) dst[tid] = sob[tid];
  }
}

extern "C" void kernel_launch(void* const* d_in, const int* in_sizes, int n_in,
                              void* d_out, int out_size, void* d_ws, size_t ws_size,
                              hipStream_t stream) {
  const float* x  = (const float*)d_in[0];
  const int* eidx = (const int*)d_in[1];
  const float* W0 = (const float*)d_in[2];
  const float* b0 = (const float*)d_in[3];
  const float* W1 = (const float*)d_in[4];
  const float* b1 = (const float*)d_in[5];
  const float* W2 = (const float*)d_in[6];
  const float* b2 = (const float*)d_in[7];
  float* out = (float*)d_out;
  unsigned short* wp = (unsigned short*)d_ws;
  if (ws_size < (size_t)WP_USHORTS * 2) return;   // ~1.04 MB minimum

  pack_weights<<<2080, 256, 0, stream>>>(W0, W1, W2, wp);
  if (ws_size >= (size_t)(WP_USHORTS + XBF_USHORTS) * 2) {
    unsigned short* xbf = wp + WP_USHORTS;
    convert_x<<<1250, 256, 0, stream>>>(x, xbf);
    edge_mlp<1><<<NTILES, 512, 0, stream>>>(x, xbf, eidx, b0, b1, b2, wp, out);
  } else {
    edge_mlp<0><<<NTILES, 512, 0, stream>>>(x, nullptr, eidx, b0, b1, b2, wp, out);
  }
}

// Round 8
// 242.965 us; speedup vs baseline: 2.4861x; 1.0024x over previous
//
#include <hip/hip_runtime.h>

#define E_TOTAL 200000
#define OUTD 5
#define NTILES 3125           // 200000 / 64 exactly, no tail
#define WP_USHORTS 532480     // W0p (262144) + W1p (262144) + W2p (8192)
#define XBF_USHORTS 2560000   // 10000 * 256 bf16 copy of x

typedef __attribute__((ext_vector_type(4))) float f32x4;
typedef __attribute__((ext_vector_type(16))) float f32x16;
typedef __attribute__((ext_vector_type(8))) __bf16 bf16x8;

static __device__ __forceinline__ unsigned short f2bf(float f) {
  union { float f; unsigned u; } v; v.f = f;
  unsigned u = v.u;
  unsigned r = (u + 0x7FFFu + ((u >> 16) & 1u)) >> 16;   // RNE
  return (unsigned short)r;
}
static __device__ __forceinline__ unsigned short f2bf_cast(float f) {
  __bf16 h = (__bf16)f;                                   // HW cvt, RNE
  return __builtin_bit_cast(unsigned short, h);
}

// ---------------------------------------------------------------------------
// Pack W0,W1 [512x512] into 32x32x16-bf16 fragment order (A- and B-operand
// layouts are transposed-symmetric: l&31 indexes the non-K dim,
// (l>>5)*8+j indexes K):  off = ((wtile*32 + ks)*64 + lane)*8 + j = W[k][n]
// W2 [512x5] padded N=16 into 16x16x32 fragment order.
// ws layout (ushort): [0,262144) W0p | [262144,524288) W1p | [524288,532480) W2p
//                     [532480, +2560000) xbf (if ws_size permits)
// ---------------------------------------------------------------------------
__global__ __launch_bounds__(256) void pack_weights(
    const float* __restrict__ W0, const float* __restrict__ W1,
    const float* __restrict__ W2, unsigned short* __restrict__ wp) {
  int tid = blockIdx.x * 256 + threadIdx.x;
  if (tid < 2 * 262144) {
    int sel = tid >> 18;
    int t = tid & 262143;
    int n = t & 511, k = t >> 9;            // coalesced read along n
    const float* W = sel ? W1 : W0;
    float val = W[k * 512 + n];
    int ntile = n >> 5, ks = k >> 4;
    int lane = (((k >> 3) & 1) << 5) | (n & 31);
    int j = k & 7;
    int off = (((ntile * 32 + ks) * 64 + lane) << 3) | j;
    wp[sel * 262144 + off] = f2bf(val);
  } else {
    int t2 = tid - 524288;
    if (t2 < 8192) {                         // W2 padded N=5 -> 16
      int j = t2 & 7, lane = (t2 >> 3) & 63, k0 = t2 >> 9;
      int k = k0 * 32 + ((lane >> 4) << 3) + j;
      int n = lane & 15;
      float val = (n < OUTD) ? W2[k * OUTD + n] : 0.0f;
      wp[524288 + t2] = f2bf(val);
    }
  }
}

// fp32 x -> bf16 copy (one-shot, memory-bound)
__global__ __launch_bounds__(256) void convert_x(
    const float* __restrict__ x, unsigned short* __restrict__ xbf) {
  int i = blockIdx.x * 256 + threadIdx.x;    // 8 elems each
  if (i < 320000) {
    const float4 f0 = *(const float4*)(x + (size_t)i * 8);
    const float4 f1 = *(const float4*)(x + (size_t)i * 8 + 4);
    uint4 pk;
    pk.x = (unsigned)f2bf(f0.x) | ((unsigned)f2bf(f0.y) << 16);
    pk.y = (unsigned)f2bf(f0.z) | ((unsigned)f2bf(f0.w) << 16);
    pk.z = (unsigned)f2bf(f1.x) | ((unsigned)f2bf(f1.y) << 16);
    pk.w = (unsigned)f2bf(f1.z) | ((unsigned)f2bf(f1.w) << 16);
    *(uint4*)(xbf + (size_t)i * 8) = pk;
  }
}

// ---------------------------------------------------------------------------
// Fused edge-MLP, OPERAND-SWAPPED: D = W(A-op) x Edges(B-op), so each lane's
// C fragment holds 16 FEATURES of ONE edge, in row-quads -> epilogue is
// 16 ds_write_b64 per wave/layer (was 64 ds_write_b16) and bias is a free
// C-init from 8 float4 loads. One block = 64 edges, 512 threads (8 waves),
// 2 blocks/CU. LDS: [64 rows][512 cols] bf16 A/H buffer (65536 B, swizzled
// byte ^= (row&7)<<4) + 1280 B out-staging.
// Wave w owns feature cols w*64..+63 (2 x 32-feature tiles) x all 64 edges
// (2 x 32-edge tiles): acc 4 x f32x16 (64 AGPRs), 32 k-steps, 2-deep weight
// prefetch, setprio around MFMA cluster. Layer 2 swapped: lane owns one edge,
// pair-mean = __shfl_xor(.,1). Feature-4 write restricted to q==1 lanes
// (q=2/3 hold zero-padded features 8/12 -> R7 race zeroed out[...,4]).
// ---------------------------------------------------------------------------
template <int XBF>
__global__ __launch_bounds__(512, 4) void edge_mlp(
    const float* __restrict__ x, const unsigned short* __restrict__ xbf,
    const int* __restrict__ eidx,
    const float* __restrict__ b0, const float* __restrict__ b1,
    const float* __restrict__ b2, const unsigned short* __restrict__ wp,
    float* __restrict__ out) {
  __shared__ uint4 ldsv[4096 + 80];           // 65536 + 1280 B
  unsigned char* lds = (unsigned char*)ldsv;
  float* obuf = (float*)(lds + 65536);        // 64*5 f32

  const int tid = threadIdx.x;
  const int lane = tid & 63;
  const int w = tid >> 6;                     // wave 0..7
  const int l31 = lane & 31, h = lane >> 5;
  const int l15 = lane & 15, q = lane >> 4;
  const unsigned t = blockIdx.x;

  // ---- stage gathered inputs: A[64][512] bf16, cols 0..255 = x[src], 256..511 = x[dst]
  {
    const int r = tid >> 3, p = tid & 7;      // 8 threads per row
    const int e = (int)t * 64 + r;            // grid exact
    const int node = eidx[(p >> 2) * E_TOTAL + e];
    const unsigned rowb = (unsigned)r * 1024;
    const unsigned sx = (unsigned)((r & 7) << 4);
    const unsigned cb0 = (unsigned)((p >> 2) * 512 + (p & 3) * 128);
    if (XBF) {
      const unsigned short* s = xbf + (size_t)node * 256 + (p & 3) * 64;
#pragma unroll
      for (int jj = 0; jj < 8; ++jj) {
        const int kk = (jj + p) & 7;          // phase by p: conflict-free writes
        uint4 pk = *(const uint4*)(s + kk * 8);
        *(uint4*)(lds + rowb + ((cb0 + (unsigned)kk * 16) ^ sx)) = pk;
      }
    } else {
      const float* s = x + (size_t)node * 256 + (p & 3) * 64;
#pragma unroll
      for (int jj = 0; jj < 8; ++jj) {
        const int kk = (jj + p) & 7;
        const float4 f0 = *(const float4*)(s + kk * 8);
        const float4 f1 = *(const float4*)(s + kk * 8 + 4);
        uint4 pk;
        pk.x = (unsigned)f2bf(f0.x) | ((unsigned)f2bf(f0.y) << 16);
        pk.y = (unsigned)f2bf(f0.z) | ((unsigned)f2bf(f0.w) << 16);
        pk.z = (unsigned)f2bf(f1.x) | ((unsigned)f2bf(f1.y) << 16);
        pk.w = (unsigned)f2bf(f1.z) | ((unsigned)f2bf(f1.w) << 16);
        *(uint4*)(lds + rowb + ((cb0 + (unsigned)kk * 16) ^ sx)) = pk;
      }
    }
  }
  __syncthreads();

  const unsigned sw = (unsigned)((l31 & 7) << 4);   // epilogue swizzle (e&7 == l31&7)

  // ===== hidden layers =====
#pragma unroll 1
  for (int L = 0; L < 2; ++L) {
    const unsigned short* wl = wp + L * 262144;
    const unsigned short* wbaseA = wl + (size_t)(w * 2) * 16384 + (size_t)lane * 8;
    const unsigned short* wbaseB = wbaseA + 16384;
    const float* bias = L ? b1 : b0;

    // bias C-init: reg 4*qd+rr -> feature ft*32 + 8*qd + 4*h + rr
    float4 bq0[4], bq1[4];
#pragma unroll
    for (int qd = 0; qd < 4; ++qd) {
      bq0[qd] = *(const float4*)(bias + w * 64 + 8 * qd + 4 * h);
      bq1[qd] = *(const float4*)(bias + w * 64 + 32 + 8 * qd + 4 * h);
    }
    f32x16 accA0, accA1, accB0, accB1;        // acc[ftile][etile]
#pragma unroll
    for (int qd = 0; qd < 4; ++qd)
#pragma unroll
      for (int rr = 0; rr < 4; ++rr) {
        accA0[4 * qd + rr] = bq0[qd][rr];
        accA1[4 * qd + rr] = bq0[qd][rr];
        accB0[4 * qd + rr] = bq1[qd][rr];
        accB1[4 * qd + rr] = bq1[qd][rr];
      }

    bf16x8 cwA = *(const bf16x8*)wbaseA;
    bf16x8 cwB = *(const bf16x8*)wbaseB;
    bf16x8 nwA = *(const bf16x8*)(wbaseA + 512);
    bf16x8 nwB = *(const bf16x8*)(wbaseB + 512);

#pragma unroll 4
    for (int ks = 0; ks < 32; ++ks) {
      const int kp = (ks + 2) & 31;           // 2-deep prefetch, branchless wrap
      bf16x8 pA = *(const bf16x8*)(wbaseA + kp * 512);
      bf16x8 pB = *(const bf16x8*)(wbaseB + kp * 512);
      const unsigned cb = (unsigned)(ks * 32 + h * 16);
      bf16x8 a0, a1;                          // edge fragments (B-operand)
      {
        const unsigned r0 = (unsigned)l31;
        const unsigned r1 = r0 + 32;
        a0 = *(const bf16x8*)(lds + r0 * 1024 + (cb ^ ((r0 & 7) << 4)));
        a1 = *(const bf16x8*)(lds + r1 * 1024 + (cb ^ ((r1 & 7) << 4)));
      }
      __builtin_amdgcn_s_setprio(1);
      accA0 = __builtin_amdgcn_mfma_f32_32x32x16_bf16(cwA, a0, accA0, 0, 0, 0);
      accA1 = __builtin_amdgcn_mfma_f32_32x32x16_bf16(cwA, a1, accA1, 0, 0, 0);
      accB0 = __builtin_amdgcn_mfma_f32_32x32x16_bf16(cwB, a0, accB0, 0, 0, 0);
      accB1 = __builtin_amdgcn_mfma_f32_32x32x16_bf16(cwB, a1, accB1, 0, 0, 0);
      __builtin_amdgcn_s_setprio(0);
      cwA = nwA; cwB = nwB; nwA = pA; nwB = pB;
    }

    __syncthreads();   // all waves done reading A/H; only AGPR acc lives across

    // relu + cvt + write H over A, b64 quads.
    // C layout: col(lane&31)=edge, row(reg) = (reg&3)+8*(reg>>2)+4h = feature
    // byte col = 2*(w*64 + ft*32 + 8*qd + 4h + rr) -> quad = 8B at
    // 128w + 64ft + 16qd + 8h, XOR (e&7)<<4.
#define EPI_TILE(ACC, FT, ET)                                                  \
    {                                                                          \
      const unsigned rowb = (unsigned)((ET) * 32 + l31) * 1024;                \
      const unsigned cbase = (unsigned)(128 * w + 64 * (FT) + 8 * h);          \
      _Pragma("unroll")                                                        \
      for (int qd = 0; qd < 4; ++qd) {                                         \
        uint2 pk2;                                                             \
        pk2.x = (unsigned)f2bf_cast(fmaxf((ACC)[4 * qd + 0], 0.f)) |           \
                ((unsigned)f2bf_cast(fmaxf((ACC)[4 * qd + 1], 0.f)) << 16);    \
        pk2.y = (unsigned)f2bf_cast(fmaxf((ACC)[4 * qd + 2], 0.f)) |           \
                ((unsigned)f2bf_cast(fmaxf((ACC)[4 * qd + 3], 0.f)) << 16);    \
        *(uint2*)(lds + rowb + ((cbase + 16u * qd) ^ sw)) = pk2;               \
      }                                                                        \
    }
    EPI_TILE(accA0, 0, 0)
    EPI_TILE(accA1, 0, 1)
    EPI_TILE(accB0, 1, 0)
    EPI_TILE(accB1, 1, 1)
#undef EPI_TILE
    __syncthreads();
  }

  // ===== layer 2 (swapped): waves 0..3, wave w -> edges w*16..w*16+15 =====
  if (w < 4) {
    f32x4 acc2; acc2[0] = 0.f; acc2[1] = 0.f; acc2[2] = 0.f; acc2[3] = 0.f;
    const unsigned short* w2b = wp + 524288 + (size_t)lane * 8;
    const unsigned row = (unsigned)(w * 16 + l15);     // edge (B-operand col)
    const unsigned rsx = (row & 7) << 4;
#pragma unroll
    for (int k0 = 0; k0 < 16; ++k0) {
      bf16x8 eF = *(const bf16x8*)(lds + row * 1024 + (((unsigned)(k0 * 64 + q * 16)) ^ rsx));
      bf16x8 wF = *(const bf16x8*)(w2b + k0 * 512);
      acc2 = __builtin_amdgcn_mfma_f32_16x16x32_bf16(wF, eF, acc2, 0, 0, 0);
    }
    // C: col(l15)=edge, row(q*4+r)=feature. Pair-mean across edges (e, e^1).
    const int e = w * 16 + l15;
#pragma unroll
    for (int r = 0; r < 4; ++r) {
      const float s = __shfl_xor(acc2[r], 1);
      const float m = 0.5f * (acc2[r] + s);
      if (q == 0) {
        obuf[e * OUTD + r] = m + b2[r];
      } else if (q == 1 && r == 0) {          // feature 4 ONLY from q==1
        obuf[e * OUTD + 4] = m + b2[4];
      }
    }
  }
  __syncthreads();

  // ===== coalesced out store (full 64B lines; 64*5*4B = 20 lines) =====
  {
    uint4* dst = (uint4*)(out + (size_t)t * 320);
    const uint4* sob = (const uint4*)obuf;
    if (tid < 80) dst[tid] = sob[tid];
  }
}

extern "C" void kernel_launch(void* const* d_in, const int* in_sizes, int n_in,
                              void* d_out, int out_size, void* d_ws, size_t ws_size,
                              hipStream_t stream) {
  const float* x  = (const float*)d_in[0];
  const int* eidx = (const int*)d_in[1];
  const float* W0 = (const float*)d_in[2];
  const float* b0 = (const float*)d_in[3];
  const float* W1 = (const float*)d_in[4];
  const float* b1 = (const float*)d_in[5];
  const float* W2 = (const float*)d_in[6];
  const float* b2 = (const float*)d_in[7];
  float* out = (float*)d_out;
  unsigned short* wp = (unsigned short*)d_ws;
  if (ws_size < (size_t)WP_USHORTS * 2) return;   // ~1.04 MB minimum

  pack_weights<<<2080, 256, 0, stream>>>(W0, W1, W2, wp);
  if (ws_size >= (size_t)(WP_USHORTS + XBF_USHORTS) * 2) {
    unsigned short* xbf = wp + WP_USHORTS;
    convert_x<<<1250, 256, 0, stream>>>(x, xbf);
    edge_mlp<1><<<NTILES, 512, 0, stream>>>(x, xbf, eidx, b0, b1, b2, wp, out);
  } else {
    edge_mlp<0><<<NTILES, 512, 0, stream>>>(x, nullptr, eidx, b0, b1, b2, wp, out);
  }
}

// Round 9
// 238.038 us; speedup vs baseline: 2.5375x; 1.0207x over previous
//
#include <hip/hip_runtime.h>

#define E_TOTAL 200000
#define OUTD 5
#define NTILES 3125           // 200000 / 64 exactly, no tail
#define WP_USHORTS 532480     // W0p (262144) + W1p (262144) + W2p (8192)
#define XBF_USHORTS 2560000   // 10000 * 256 bf16 copy of x

typedef __attribute__((ext_vector_type(4))) float f32x4;
typedef __attribute__((ext_vector_type(16))) float f32x16;
typedef __attribute__((ext_vector_type(8))) __bf16 bf16x8;

static __device__ __forceinline__ unsigned short f2bf(float f) {
  union { float f; unsigned u; } v; v.f = f;
  unsigned u = v.u;
  unsigned r = (u + 0x7FFFu + ((u >> 16) & 1u)) >> 16;   // RNE
  return (unsigned short)r;
}
static __device__ __forceinline__ unsigned short f2bf_cast(float f) {
  __bf16 h = (__bf16)f;                                   // HW cvt, RNE
  return __builtin_bit_cast(unsigned short, h);
}

// ---------------------------------------------------------------------------
// Pack W0,W1 [512x512] into 32x32x16-bf16 fragment order:
//   off = ((wtile*32 + ks)*64 + lane)*8 + j, value = W[k][n]
// W2 [512x5] padded N=16 into 16x16x32 fragment order.
// ws layout (ushort): [0,262144) W0p | [262144,524288) W1p | [524288,532480) W2p
//                     [532480, +2560000) xbf (if ws_size permits)
// ---------------------------------------------------------------------------
__global__ __launch_bounds__(256) void pack_weights(
    const float* __restrict__ W0, const float* __restrict__ W1,
    const float* __restrict__ W2, unsigned short* __restrict__ wp) {
  int tid = blockIdx.x * 256 + threadIdx.x;
  if (tid < 2 * 262144) {
    int sel = tid >> 18;
    int t = tid & 262143;
    int n = t & 511, k = t >> 9;            // coalesced read along n
    const float* W = sel ? W1 : W0;
    float val = W[k * 512 + n];
    int ntile = n >> 5, ks = k >> 4;
    int lane = (((k >> 3) & 1) << 5) | (n & 31);
    int j = k & 7;
    int off = (((ntile * 32 + ks) * 64 + lane) << 3) | j;
    wp[sel * 262144 + off] = f2bf(val);
  } else {
    int t2 = tid - 524288;
    if (t2 < 8192) {                         // W2 padded N=5 -> 16
      int j = t2 & 7, lane = (t2 >> 3) & 63, k0 = t2 >> 9;
      int k = k0 * 32 + ((lane >> 4) << 3) + j;
      int n = lane & 15;
      float val = (n < OUTD) ? W2[k * OUTD + n] : 0.0f;
      wp[524288 + t2] = f2bf(val);
    }
  }
}

// fp32 x -> bf16 copy (one-shot, memory-bound)
__global__ __launch_bounds__(256) void convert_x(
    const float* __restrict__ x, unsigned short* __restrict__ xbf) {
  int i = blockIdx.x * 256 + threadIdx.x;    // 8 elems each
  if (i < 320000) {
    const float4 f0 = *(const float4*)(x + (size_t)i * 8);
    const float4 f1 = *(const float4*)(x + (size_t)i * 8 + 4);
    uint4 pk;
    pk.x = (unsigned)f2bf(f0.x) | ((unsigned)f2bf(f0.y) << 16);
    pk.y = (unsigned)f2bf(f0.z) | ((unsigned)f2bf(f0.w) << 16);
    pk.z = (unsigned)f2bf(f1.x) | ((unsigned)f2bf(f1.y) << 16);
    pk.w = (unsigned)f2bf(f1.z) | ((unsigned)f2bf(f1.w) << 16);
    *(uint4*)(xbf + (size_t)i * 8) = pk;
  }
}

// ---------------------------------------------------------------------------
// Fused edge-MLP, operand-swapped, 4-WAVE blocks (halved LDS amplification):
// One block = 64 edges, 256 threads (4 waves), 2 blocks/CU.
// Wave w owns features w*128..+127 (4 x 32-ft tiles) x 64 edges (2 x 32-edge
// tiles): acc = 8 x f32x16 (128 AGPRs), bias as C-init, depth-1 weight
// prefetch (4 tiles), 2 ds_read_b128 feed 8 MFMAs (256 pipe-cyc) per k-step.
// LDS k-loop reads: 4 waves x 64KB x 2 layers = 512KB/block (was 1MB).
// LDS: [64 rows][512 cols] bf16 A/H (65536 B, swizzle byte^=(row&7)<<4)
// + 1280 B obuf. Layer 2: 4 waves x 16 edges, pair-mean via __shfl_xor(.,1);
// feature-4 written only by q==1 (R7 race lesson).
// VGPR budget: ~95 VGPR + 128 AGPR = ~223 <= 256 cap at (256,2).
// ---------------------------------------------------------------------------
template <int XBF>
__global__ __launch_bounds__(256, 2) void edge_mlp(
    const float* __restrict__ x, const unsigned short* __restrict__ xbf,
    const int* __restrict__ eidx,
    const float* __restrict__ b0, const float* __restrict__ b1,
    const float* __restrict__ b2, const unsigned short* __restrict__ wp,
    float* __restrict__ out) {
  __shared__ uint4 ldsv[4096 + 80];           // 65536 + 1280 B
  unsigned char* lds = (unsigned char*)ldsv;
  float* obuf = (float*)(lds + 65536);        // 64*5 f32

  const int tid = threadIdx.x;
  const int lane = tid & 63;
  const int w = tid >> 6;                     // wave 0..3
  const int l31 = lane & 31, h = lane >> 5;
  const int l15 = lane & 15, q = lane >> 4;
  const unsigned t = blockIdx.x;

  // ---- stage gathered inputs: A[64][512] bf16, cols 0..255 = x[src], 256..511 = x[dst]
  {
    const int p = tid & 7;                    // 8 threads per row, 2 passes
#pragma unroll
    for (int pass = 0; pass < 2; ++pass) {
      const int r = (tid >> 3) + 32 * pass;
      const int e = (int)t * 64 + r;          // grid exact
      const int node = eidx[(p >> 2) * E_TOTAL + e];
      const unsigned rowb = (unsigned)r * 1024;
      const unsigned sx = (unsigned)((r & 7) << 4);
      const unsigned cb0 = (unsigned)((p >> 2) * 512 + (p & 3) * 128);
      if (XBF) {
        const unsigned short* s = xbf + (size_t)node * 256 + (p & 3) * 64;
#pragma unroll
        for (int jj = 0; jj < 8; ++jj) {
          const int kk = (jj + p) & 7;        // phase by p: conflict-spread writes
          uint4 pk = *(const uint4*)(s + kk * 8);
          *(uint4*)(lds + rowb + ((cb0 + (unsigned)kk * 16) ^ sx)) = pk;
        }
      } else {
        const float* s = x + (size_t)node * 256 + (p & 3) * 64;
#pragma unroll
        for (int jj = 0; jj < 8; ++jj) {
          const int kk = (jj + p) & 7;
          const float4 f0 = *(const float4*)(s + kk * 8);
          const float4 f1 = *(const float4*)(s + kk * 8 + 4);
          uint4 pk;
          pk.x = (unsigned)f2bf(f0.x) | ((unsigned)f2bf(f0.y) << 16);
          pk.y = (unsigned)f2bf(f0.z) | ((unsigned)f2bf(f0.w) << 16);
          pk.z = (unsigned)f2bf(f1.x) | ((unsigned)f2bf(f1.y) << 16);
          pk.w = (unsigned)f2bf(f1.z) | ((unsigned)f2bf(f1.w) << 16);
          *(uint4*)(lds + rowb + ((cb0 + (unsigned)kk * 16) ^ sx)) = pk;
        }
      }
    }
  }
  __syncthreads();

  const unsigned sx31 = (unsigned)((l31 & 7) << 4);  // k-loop read & epi swizzle

  // ===== hidden layers =====
#pragma unroll 1
  for (int L = 0; L < 2; ++L) {
    const unsigned short* wl = wp + L * 262144;
    const unsigned short* wbA = wl + (size_t)(4 * w) * 16384 + (size_t)lane * 8;
    const unsigned short* wbB = wbA + 16384;
    const unsigned short* wbC = wbA + 32768;
    const unsigned short* wbD = wbA + 49152;
    const float* bias = L ? b1 : b0;

    // bias C-init: reg 4*qd+rr -> feature w*128 + F*32 + 8*qd + 4*h + rr
    f32x16 aA0, aA1, aB0, aB1, aC0, aC1, aD0, aD1;
#define BINIT(ACC0, ACC1, F)                                                   \
    {                                                                          \
      _Pragma("unroll")                                                        \
      for (int qd = 0; qd < 4; ++qd) {                                         \
        const float4 bq = *(const float4*)(bias + w * 128 + (F) * 32 + 8 * qd + 4 * h); \
        _Pragma("unroll")                                                      \
        for (int rr = 0; rr < 4; ++rr) {                                       \
          (ACC0)[4 * qd + rr] = bq[rr];                                        \
          (ACC1)[4 * qd + rr] = bq[rr];                                        \
        }                                                                      \
      }                                                                        \
    }
    BINIT(aA0, aA1, 0) BINIT(aB0, aB1, 1) BINIT(aC0, aC1, 2) BINIT(aD0, aD1, 3)
#undef BINIT

    bf16x8 cwA = *(const bf16x8*)wbA;
    bf16x8 cwB = *(const bf16x8*)wbB;
    bf16x8 cwC = *(const bf16x8*)wbC;
    bf16x8 cwD = *(const bf16x8*)wbD;

#pragma unroll 2
    for (int ks = 0; ks < 32; ++ks) {
      const int kp = (ks + 1) & 31;           // depth-1 prefetch, branchless wrap
      bf16x8 nwA = *(const bf16x8*)(wbA + kp * 512);
      bf16x8 nwB = *(const bf16x8*)(wbB + kp * 512);
      bf16x8 nwC = *(const bf16x8*)(wbC + kp * 512);
      bf16x8 nwD = *(const bf16x8*)(wbD + kp * 512);
      const unsigned cb = (unsigned)(ks * 32 + h * 16);
      bf16x8 e0 = *(const bf16x8*)(lds + (unsigned)l31 * 1024 + (cb ^ sx31));
      bf16x8 e1 = *(const bf16x8*)(lds + (unsigned)(32 + l31) * 1024 + (cb ^ sx31));
      __builtin_amdgcn_s_setprio(1);
      aA0 = __builtin_amdgcn_mfma_f32_32x32x16_bf16(cwA, e0, aA0, 0, 0, 0);
      aB0 = __builtin_amdgcn_mfma_f32_32x32x16_bf16(cwB, e0, aB0, 0, 0, 0);
      aC0 = __builtin_amdgcn_mfma_f32_32x32x16_bf16(cwC, e0, aC0, 0, 0, 0);
      aD0 = __builtin_amdgcn_mfma_f32_32x32x16_bf16(cwD, e0, aD0, 0, 0, 0);
      aA1 = __builtin_amdgcn_mfma_f32_32x32x16_bf16(cwA, e1, aA1, 0, 0, 0);
      aB1 = __builtin_amdgcn_mfma_f32_32x32x16_bf16(cwB, e1, aB1, 0, 0, 0);
      aC1 = __builtin_amdgcn_mfma_f32_32x32x16_bf16(cwC, e1, aC1, 0, 0, 0);
      aD1 = __builtin_amdgcn_mfma_f32_32x32x16_bf16(cwD, e1, aD1, 0, 0, 0);
      __builtin_amdgcn_s_setprio(0);
      cwA = nwA; cwB = nwB; cwC = nwC; cwD = nwD;
    }

    __syncthreads();   // all waves done reading A/H; only AGPR acc lives across

    // relu + cvt + write H over A, b64 quads.
    // C layout: col(lane&31)=edge, row(reg)=(reg&3)+8*(reg>>2)+4h = feature
    // quad byte col = 256w + 64*F + 16qd + 8h, XOR (edge&7)<<4.
#define EPI_TILE(ACC, F, ET)                                                   \
    {                                                                          \
      const unsigned rowb = (unsigned)((ET) * 32 + l31) * 1024;                \
      const unsigned cbase = (unsigned)(256 * w + 64 * (F) + 8 * h);           \
      _Pragma("unroll")                                                        \
      for (int qd = 0; qd < 4; ++qd) {                                         \
        uint2 pk2;                                                             \
        pk2.x = (unsigned)f2bf_cast(fmaxf((ACC)[4 * qd + 0], 0.f)) |           \
                ((unsigned)f2bf_cast(fmaxf((ACC)[4 * qd + 1], 0.f)) << 16);    \
        pk2.y = (unsigned)f2bf_cast(fmaxf((ACC)[4 * qd + 2], 0.f)) |           \
                ((unsigned)f2bf_cast(fmaxf((ACC)[4 * qd + 3], 0.f)) << 16);    \
        *(uint2*)(lds + rowb + ((cbase + 16u * qd) ^ sx31)) = pk2;             \
      }                                                                        \
    }
    EPI_TILE(aA0, 0, 0) EPI_TILE(aA1, 0, 1)
    EPI_TILE(aB0, 1, 0) EPI_TILE(aB1, 1, 1)
    EPI_TILE(aC0, 2, 0) EPI_TILE(aC1, 2, 1)
    EPI_TILE(aD0, 3, 0) EPI_TILE(aD1, 3, 1)
#undef EPI_TILE
    __syncthreads();
  }

  // ===== layer 2 (swapped): wave w -> edges w*16..w*16+15, N=16 padded =====
  {
    f32x4 acc2; acc2[0] = 0.f; acc2[1] = 0.f; acc2[2] = 0.f; acc2[3] = 0.f;
    const unsigned short* w2b = wp + 524288 + (size_t)lane * 8;
    const unsigned row = (unsigned)(w * 16 + l15);     // edge (B-operand col)
    const unsigned rsx = (row & 7) << 4;
#pragma unroll
    for (int k0 = 0; k0 < 16; ++k0) {
      bf16x8 eF = *(const bf16x8*)(lds + row * 1024 + (((unsigned)(k0 * 64 + q * 16)) ^ rsx));
      bf16x8 wF = *(const bf16x8*)(w2b + k0 * 512);
      acc2 = __builtin_amdgcn_mfma_f32_16x16x32_bf16(wF, eF, acc2, 0, 0, 0);
    }
    // C: col(l15)=edge, row(q*4+r)=feature. Pair-mean across edges (e, e^1).
    const int e = w * 16 + l15;
#pragma unroll
    for (int r = 0; r < 4; ++r) {
      const float s = __shfl_xor(acc2[r], 1);
      const float m = 0.5f * (acc2[r] + s);
      if (q == 0) {
        obuf[e * OUTD + r] = m + b2[r];
      } else if (q == 1 && r == 0) {          // feature 4 ONLY from q==1
        obuf[e * OUTD + 4] = m + b2[4];
      }
    }
  }
  __syncthreads();

  // ===== coalesced out store (full 64B lines; 64*5*4B = 20 lines) =====
  {
    uint4* dst = (uint4*)(out + (size_t)t * 320);
    const uint4* sob = (const uint4*)obuf;
    if (tid < 80) dst[tid] = sob[tid];
  }
}

extern "C" void kernel_launch(void* const* d_in, const int* in_sizes, int n_in,
                              void* d_out, int out_size, void* d_ws, size_t ws_size,
                              hipStream_t stream) {
  const float* x  = (const float*)d_in[0];
  const int* eidx = (const int*)d_in[1];
  const float* W0 = (const float*)d_in[2];
  const float* b0 = (const float*)d_in[3];
  const float* W1 = (const float*)d_in[4];
  const float* b1 = (const float*)d_in[5];
  const float* W2 = (const float*)d_in[6];
  const float* b2 = (const float*)d_in[7];
  float* out = (float*)d_out;
  unsigned short* wp = (unsigned short*)d_ws;
  if (ws_size < (size_t)WP_USHORTS * 2) return;   // ~1.04 MB minimum

  pack_weights<<<2080, 256, 0, stream>>>(W0, W1, W2, wp);
  if (ws_size >= (size_t)(WP_USHORTS + XBF_USHORTS) * 2) {
    unsigned short* xbf = wp + WP_USHORTS;
    convert_x<<<1250, 256, 0, stream>>>(x, xbf);
    edge_mlp<1><<<NTILES, 256, 0, stream>>>(x, xbf, eidx, b0, b1, b2, wp, out);
  } else {
    edge_mlp<0><<<NTILES, 256, 0, stream>>>(x, nullptr, eidx, b0, b1, b2, wp, out);
  }
}